// Round 1
// baseline (120.137 us; speedup 1.0000x reference)
//
#include <hip/hip_runtime.h>

// Edge detector stencil, reference: _get_edges with NTR=4, DTR=0.0, DELTA=3.
// Input  x: [16, 3, 512, 512] f32  -> treated as 48 planes of 512x512.
// Output  : [16, 24, 512, 512] f32 = [48, 8, 512, 512] flat.
// Padded image im_b is ones outside [0,H)x[0,W); all consumed roll accesses
// stay within the 3-wide pad (no wraparound), so ld() returns 1.0f OOB.

#define IMG_H 512
#define IMG_W 512

__global__ __launch_bounds__(256) void edge_kernel(const float* __restrict__ in,
                                                   float* __restrict__ out,
                                                   int nimg) {
    int idx = blockIdx.x * blockDim.x + threadIdx.x;
    int w = idx & (IMG_W - 1);
    int h = (idx >> 9) & (IMG_H - 1);
    int n = idx >> 18;
    if (n >= nimg) return;

    const float* img = in + (size_t)n * IMG_H * IMG_W;

    auto ld = [&](int hh, int ww) -> float {
        bool ib = (hh >= 0) & (hh < IMG_H) & (ww >= 0) & (ww < IMG_W);
        int hc = min(max(hh, 0), IMG_H - 1);
        int wc = min(max(ww, 0), IMG_W - 1);
        float v = img[hc * IMG_W + wc];
        return ib ? v : 1.0f;
    };

    // 13-point neighborhood (padded coords (i,j)=(h+3,w+3) relative names)
    float p_cc   = ld(h,     w);
    float p_mm   = ld(h - 1, w - 1);
    float p_m0   = ld(h - 1, w);
    float p_mp   = ld(h - 1, w + 1);
    float p_0m   = ld(h,     w - 1);
    float p_0p   = ld(h,     w + 1);
    float p_pm   = ld(h + 1, w - 1);
    float p_p0   = ld(h + 1, w);
    float p_pp   = ld(h + 1, w + 1);
    float p_0mm  = ld(h,     w - 2);
    float p_mm0  = ld(h - 2, w);
    float p_mmmm = ld(h - 2, w - 2);
    float p_ppmm = ld(h + 2, w - 2);

    // Center diffs (diff_s[i,j] = P(i - s) - P(i) with roll semantics)
    float d10   = p_m0 - p_cc;   // r(+1,0)
    float dn10  = p_p0 - p_cc;   // r(-1,0)
    float d01   = p_0m - p_cc;   // r(0,+1)
    float dn01  = p_0p - p_cc;   // r(0,-1)
    float d11   = p_mm - p_cc;   // r(+1,+1)
    float dnn11 = p_pp - p_cc;   // r(-1,-1)
    float dn11  = p_pm - p_cc;   // r(-1,+1)
    float d1n1  = p_mp - p_cc;   // r(+1,-1)

    float a10 = fabsf(d10),  an10  = fabsf(dn10);
    float a01 = fabsf(d01),  an01  = fabsf(dn01);
    float a11 = fabsf(d11),  ann11 = fabsf(dnn11);
    float an11 = fabsf(dn11), a1n1 = fabsf(d1n1);

    // c10: note term 4 == term 6 in reference (counted twice)
    int c10 = (int)(a10 > a01) + (int)(a10 > an01) + (int)(a10 > an10)
            + 2 * (int)(a10 > fabsf(p_mm - p_m0))
            + (int)(a10 > fabsf(p_mp - p_m0));

    int c01 = (int)(a01 > a10) + (int)(a01 > an10) + (int)(a01 > an01)
            + (int)(a01 > fabsf(p_mm - p_0m))
            + (int)(a01 > fabsf(p_pm - p_0m))
            + (int)(a01 > fabsf(p_0mm - p_0m));

    int c11 = (int)(a11 > an11) + (int)(a11 > a1n1) + (int)(a11 > ann11)
            + (int)(a11 > fabsf(p_0mm - p_mm))
            + (int)(a11 > fabsf(p_mm0 - p_mm))
            + (int)(a11 > fabsf(p_mmmm - p_mm));

    // cn11: note term 5 == term 6 in reference (counted twice)
    int cn11 = (int)(an11 > a11) + (int)(an11 > a1n1) + (int)(an11 > ann11)
             + (int)(an11 > fabsf(p_0mm - p_pm))
             + 2 * (int)(an11 > fabsf(p_ppmm - p_pm));

    bool ok10 = c10 > 4, ok01 = c01 > 4, ok11 = c11 > 4, okn11 = cn11 > 4;
    bool hge2 = h >= 2, hlt = h < IMG_H - 2, wge2 = w >= 2, wlt = w < IMG_W - 2;

    float o0 = (ok10  && d10  > 0.f && hge2)        ? 1.f : 0.f;
    float o1 = (ok10  && d10  < 0.f && hlt)         ? 1.f : 0.f;
    float o2 = (ok01  && d01  > 0.f && wge2)        ? 1.f : 0.f;
    float o3 = (ok01  && d01  < 0.f && wlt)         ? 1.f : 0.f;
    float o4 = (ok11  && d11  > 0.f && hge2 && wge2) ? 1.f : 0.f;
    float o5 = (ok11  && d11  < 0.f && hlt  && wlt)  ? 1.f : 0.f;
    float o6 = (okn11 && dn11 > 0.f && hlt  && wge2) ? 1.f : 0.f;
    float o7 = (okn11 && dn11 < 0.f && hge2 && wlt)  ? 1.f : 0.f;

    const size_t cs = (size_t)IMG_H * IMG_W;
    size_t base = ((size_t)n * 8) * cs + (size_t)h * IMG_W + w;
    out[base]          = o0;
    out[base + cs]     = o1;
    out[base + 2 * cs] = o2;
    out[base + 3 * cs] = o3;
    out[base + 4 * cs] = o4;
    out[base + 5 * cs] = o5;
    out[base + 6 * cs] = o6;
    out[base + 7 * cs] = o7;
}

extern "C" void kernel_launch(void* const* d_in, const int* in_sizes, int n_in,
                              void* d_out, int out_size, void* d_ws, size_t ws_size,
                              hipStream_t stream) {
    const float* x = (const float*)d_in[0];
    float* out = (float*)d_out;
    int nimg = in_sizes[0] / (IMG_H * IMG_W);   // 16*3 = 48
    int total = nimg * IMG_H * IMG_W;           // 12,582,912
    int block = 256;
    int grid = (total + block - 1) / block;
    edge_kernel<<<grid, block, 0, stream>>>(x, out, nimg);
}

// Round 2
// 82.947 us; speedup vs baseline: 1.4484x; 1.4484x over previous
//
#include <hip/hip_runtime.h>

// Edge detector stencil, reference: _get_edges with NTR=4, DTR=0.0, DELTA=3.
// Input  x: [16, 3, 512, 512] f32  -> 48 planes of 512x512.
// Output  : [16, 24, 512, 512] f32 = [48, 8, 512, 512] flat.
// 4 pixels per thread along w; float4 nontemporal stores per plane.

#define IMG_H 512
#define IMG_W 512

typedef float float4v __attribute__((ext_vector_type(4)));

// Core per-pixel edge logic, no boundary gating (interior use).
// Returns 8 edge outputs in o[8].
__device__ __forceinline__ void edge_core(
    float pcc, float pmm, float pm0, float pmp,
    float p0m, float p0p, float ppm, float pp0, float ppp,
    float p0mm, float pmm0, float pmmmm, float pppmm,
    float o[8])
{
    float d10   = pm0 - pcc;
    float dn10  = pp0 - pcc;
    float d01   = p0m - pcc;
    float dn01  = p0p - pcc;
    float d11   = pmm - pcc;
    float dnn11 = ppp - pcc;
    float dn11  = ppm - pcc;
    float d1n1  = pmp - pcc;

    float a10 = fabsf(d10),  an10  = fabsf(dn10);
    float a01 = fabsf(d01),  an01  = fabsf(dn01);
    float a11 = fabsf(d11),  ann11 = fabsf(dnn11);
    float an11 = fabsf(dn11), a1n1 = fabsf(d1n1);

    int c10 = (int)(a10 > a01) + (int)(a10 > an01) + (int)(a10 > an10)
            + 2 * (int)(a10 > fabsf(pmm - pm0))
            + (int)(a10 > fabsf(pmp - pm0));

    int c01 = (int)(a01 > a10) + (int)(a01 > an10) + (int)(a01 > an01)
            + (int)(a01 > fabsf(pmm - p0m))
            + (int)(a01 > fabsf(ppm - p0m))
            + (int)(a01 > fabsf(p0mm - p0m));

    int c11 = (int)(a11 > an11) + (int)(a11 > a1n1) + (int)(a11 > ann11)
            + (int)(a11 > fabsf(p0mm - pmm))
            + (int)(a11 > fabsf(pmm0 - pmm))
            + (int)(a11 > fabsf(pmmmm - pmm));

    int cn11 = (int)(an11 > a11) + (int)(an11 > a1n1) + (int)(an11 > ann11)
             + (int)(an11 > fabsf(p0mm - ppm))
             + 2 * (int)(an11 > fabsf(pppmm - ppm));

    o[0] = (c10 > 4 && d10 > 0.f) ? 1.f : 0.f;
    o[1] = (c10 > 4 && d10 < 0.f) ? 1.f : 0.f;
    o[2] = (c01 > 4 && d01 > 0.f) ? 1.f : 0.f;
    o[3] = (c01 > 4 && d01 < 0.f) ? 1.f : 0.f;
    o[4] = (c11 > 4 && d11 > 0.f) ? 1.f : 0.f;
    o[5] = (c11 > 4 && d11 < 0.f) ? 1.f : 0.f;
    o[6] = (cn11 > 4 && dn11 > 0.f) ? 1.f : 0.f;
    o[7] = (cn11 > 4 && dn11 < 0.f) ? 1.f : 0.f;
}

__global__ __launch_bounds__(256) void edge_kernel(const float* __restrict__ in,
                                                   float* __restrict__ out,
                                                   int nimg) {
    int idx = blockIdx.x * blockDim.x + threadIdx.x;
    int wq = idx & (IMG_W / 4 - 1);      // 0..127
    int h = (idx >> 7) & (IMG_H - 1);
    int n = idx >> 16;
    if (n >= nimg) return;
    int w0 = wq * 4;

    const float* img = in + (size_t)n * IMG_H * IMG_W;

    float4v ov[8];

    bool interior = (h >= 2) & (h <= IMG_H - 3) & (w0 >= 4) & (w0 <= IMG_W - 8);

    if (interior) {
        // Window loads: rows h-2..h+2, contiguous spans.
        const float* rowm2 = img + (h - 2) * IMG_W + w0;
        const float* rowm1 = img + (h - 1) * IMG_W + w0;
        const float* row0  = img + h * IMG_W + w0;
        const float* rowp1 = img + (h + 1) * IMG_W + w0;
        const float* rowp2 = img + (h + 2) * IMG_W + w0;

        float rm2[6], rm1[6], r0[7], rp1[6], rp2[4];
#pragma unroll
        for (int j = 0; j < 6; ++j) rm2[j] = rowm2[j - 2];   // cols w0-2..w0+3
#pragma unroll
        for (int j = 0; j < 6; ++j) rm1[j] = rowm1[j - 1];   // cols w0-1..w0+4
#pragma unroll
        for (int j = 0; j < 7; ++j) r0[j]  = row0[j - 2];    // cols w0-2..w0+4
#pragma unroll
        for (int j = 0; j < 6; ++j) rp1[j] = rowp1[j - 1];   // cols w0-1..w0+4
#pragma unroll
        for (int j = 0; j < 4; ++j) rp2[j] = rowp2[j - 2];   // cols w0-2..w0+1

#pragma unroll
        for (int i = 0; i < 4; ++i) {
            float o[8];
            edge_core(r0[i + 2],            // pcc
                      rm1[i], rm1[i + 1], rm1[i + 2],
                      r0[i + 1], r0[i + 3],
                      rp1[i], rp1[i + 1], rp1[i + 2],
                      r0[i],                // p0mm (w-2)
                      rm2[i + 2],           // pmm0 (h-2, w)
                      rm2[i],               // pmmmm (h-2, w-2)
                      rp2[i],               // pppmm (h+2, w-2)
                      o);
#pragma unroll
            for (int k = 0; k < 8; ++k) ov[k][i] = o[k];
        }
    } else {
        auto ld = [&](int hh, int ww) -> float {
            bool ib = (hh >= 0) & (hh < IMG_H) & (ww >= 0) & (ww < IMG_W);
            int hc = min(max(hh, 0), IMG_H - 1);
            int wc = min(max(ww, 0), IMG_W - 1);
            float v = img[hc * IMG_W + wc];
            return ib ? v : 1.0f;
        };
#pragma unroll
        for (int i = 0; i < 4; ++i) {
            int w = w0 + i;
            float o[8];
            edge_core(ld(h, w),
                      ld(h - 1, w - 1), ld(h - 1, w), ld(h - 1, w + 1),
                      ld(h, w - 1), ld(h, w + 1),
                      ld(h + 1, w - 1), ld(h + 1, w), ld(h + 1, w + 1),
                      ld(h, w - 2),
                      ld(h - 2, w),
                      ld(h - 2, w - 2),
                      ld(h + 2, w - 2),
                      o);
            // Boundary gating
            bool hge2 = h >= 2, hlt = h < IMG_H - 2;
            bool wge2 = w >= 2, wlt = w < IMG_W - 2;
            ov[0][i] = (hge2)         ? o[0] : 0.f;
            ov[1][i] = (hlt)          ? o[1] : 0.f;
            ov[2][i] = (wge2)         ? o[2] : 0.f;
            ov[3][i] = (wlt)          ? o[3] : 0.f;
            ov[4][i] = (hge2 && wge2) ? o[4] : 0.f;
            ov[5][i] = (hlt && wlt)   ? o[5] : 0.f;
            ov[6][i] = (hlt && wge2)  ? o[6] : 0.f;
            ov[7][i] = (hge2 && wlt)  ? o[7] : 0.f;
        }
    }

    const size_t cs = (size_t)IMG_H * IMG_W;
    float* obase = out + ((size_t)n * 8) * cs + (size_t)h * IMG_W + w0;
#pragma unroll
    for (int k = 0; k < 8; ++k) {
        __builtin_nontemporal_store(ov[k], (float4v*)(obase + (size_t)k * cs));
    }
}

extern "C" void kernel_launch(void* const* d_in, const int* in_sizes, int n_in,
                              void* d_out, int out_size, void* d_ws, size_t ws_size,
                              hipStream_t stream) {
    const float* x = (const float*)d_in[0];
    float* out = (float*)d_out;
    int nimg = in_sizes[0] / (IMG_H * IMG_W);            // 48
    long long total = (long long)nimg * IMG_H * (IMG_W / 4);  // threads
    int block = 256;
    int grid = (int)((total + block - 1) / block);
    edge_kernel<<<grid, block, 0, stream>>>(x, out, nimg);
}